// Round 12
// baseline (126.579 us; speedup 1.0000x reference)
//
#include <hip/hip_runtime.h>

#define HW   4096
#define HIMG 64
#define WIMG 64
#define CC   256
#define CR   32
#define B_   8

typedef __attribute__((ext_vector_type(8))) short bf16x8;
typedef __attribute__((ext_vector_type(4))) float f32x4;

__device__ inline unsigned short f2bf(float f) {
    union { float f; unsigned u; } v; v.f = f;
    return (unsigned short)((v.u + 0x8000u) >> 16);
}
__device__ inline float bf2f(unsigned short h) {
    union { unsigned u; float f; } v; v.u = ((unsigned)h) << 16; return v.f;
}
__device__ inline unsigned pack2(float a, float b) {
    return (unsigned)f2bf(a) | ((unsigned)f2bf(b) << 16);
}
// XCD-contiguous h mapping (bijective 3-bit rotate on [0,64)):
// block hx dispatches to XCD hx%8 (linear round-robin; the +64*b term is
// ==0 mod 8, so mapping is b-independent).  hswz gives XCD i the contiguous
// slab h in [8i, 8i+8): vv/k halo rows (h±1) and proj->attn producer-
// consumer reuse become intra-XCD L2 hits instead of HBM re-fetches.
// Used consistently by BOTH kernels.  Perf heuristic only.
__device__ inline int hswz(int hx) { return ((hx & 7) << 3) | (hx >> 3); }

// ---------------------------------------------------------------------------
// K1: fused transpose+convert+GEMM (R11 body, byte-identical arithmetic).
// CHANGED vs R11 (single variable): hw-tile index = hswz(blockIdx.x).
// ---------------------------------------------------------------------------
__global__ __launch_bounds__(256) void proj_gemm(
    const float* __restrict__ Wq, const float* __restrict__ bq,
    const float* __restrict__ Wk, const float* __restrict__ bk,
    const float* __restrict__ Wv, const float* __restrict__ bv,
    const float* __restrict__ x,
    unsigned short* __restrict__ q, unsigned short* __restrict__ k,
    unsigned short* __restrict__ vv)
{
    __shared__ unsigned short As[320 * 72];
    __shared__ float          xt32[64 * 65];
    __shared__ unsigned short Bs[64 * 64];

    const int b   = blockIdx.y;
    const int hw0 = hswz(blockIdx.x) * 64;
    const int t    = threadIdx.x;
    const int lane = t & 63, wv = t >> 6;
    const int m16  = lane & 15, quad = lane >> 4;

    f32x4 acc[5][4];
    #pragma unroll
    for (int i = 0; i < 5; ++i)
        #pragma unroll
        for (int n = 0; n < 4; ++n)
            acc[i][n] = (f32x4){0.f, 0.f, 0.f, 0.f};

    for (int kc = 0; kc < 4; ++kc) {
        const int k0 = kc * 64;
        if (kc) __syncthreads();            // protect As/xt32/Bs reuse

        // stage A: 320 rows x 64 ch, fp32 source -> bf16 inline (same f2bf)
        #pragma unroll
        for (int i = 0; i < 10; ++i) {
            int idx = t + 256 * i;          // 0..2559
            int row = idx >> 3, s8 = idx & 7;
            const float* wsrc = (row < 32) ? &Wq[row * CC]
                              : (row < 64) ? &Wk[(row - 32) * CC]
                                           : &Wv[(row - 64) * CC];
            float4 a0 = *(const float4*)&wsrc[k0 + s8 * 8];
            float4 a1 = *(const float4*)&wsrc[k0 + s8 * 8 + 4];
            uint4 u;
            u.x = pack2(a0.x, a0.y); u.y = pack2(a0.z, a0.w);
            u.z = pack2(a1.x, a1.y); u.w = pack2(a1.z, a1.w);
            *(uint4*)&As[row * 72 + s8 * 8] = u;
        }
        // stage x chunk fp32: 64 c x 64 px, coalesced along px
        #pragma unroll
        for (int i = 0; i < 4; ++i) {
            int idx = t + 256 * i;          // 0..1023
            int c = idx >> 4, p4 = (idx & 15) * 4;
            float4 vx = *(const float4*)&x[((size_t)b * CC + k0 + c) * HW + hw0 + p4];
            *(float4*)&xt32[c * 65 + p4] = vx;
        }
        __syncthreads();

        // transpose+convert into Bs: thread -> px = lane, 16 channels
        {
            const int px = lane;
            const int c0 = wv * 16;
            float f[16];
            #pragma unroll
            for (int j = 0; j < 16; ++j)
                f[j] = xt32[(c0 + j) * 65 + px];   // bank (c0+j+px)%32: 2-way
            uint4 w0, w1;
            w0.x = pack2(f[0],  f[1]);  w0.y = pack2(f[2],  f[3]);
            w0.z = pack2(f[4],  f[5]);  w0.w = pack2(f[6],  f[7]);
            w1.x = pack2(f[8],  f[9]);  w1.y = pack2(f[10], f[11]);
            w1.z = pack2(f[12], f[13]); w1.w = pack2(f[14], f[15]);
            const int lg0 = c0 >> 3, sw = px & 7;
            *(uint4*)&Bs[px * 64 + ((lg0     ^ sw) * 8)] = w0;
            *(uint4*)&Bs[px * 64 + (((lg0+1) ^ sw) * 8)] = w1;
        }
        __syncthreads();

        #pragma unroll
        for (int ks = 0; ks < 2; ++ks) {
            bf16x8 af[5], bf[4];
            #pragma unroll
            for (int i = 0; i < 5; ++i)
                af[i] = *(const bf16x8*)&As[((wv * 5 + i) * 16 + m16) * 72
                                            + ks * 32 + quad * 8];
            #pragma unroll
            for (int n = 0; n < 4; ++n) {
                int px = n * 16 + m16;
                int lg = ks * 4 + quad;
                bf[n] = *(const bf16x8*)&Bs[px * 64 + ((lg ^ (px & 7)) * 8)];
            }
            #pragma unroll
            for (int i = 0; i < 5; ++i)
                #pragma unroll
                for (int n = 0; n < 4; ++n)
                    acc[i][n] = __builtin_amdgcn_mfma_f32_16x16x32_bf16(
                        af[i], bf[n], acc[i][n], 0, 0, 0);
        }
    }

    // epilogue: D row = quad*4+reg, col = lane&15; biases direct from inputs
    #pragma unroll
    for (int i = 0; i < 5; ++i) {
        const int ob = (wv * 5 + i) * 16;        // 0..304, wave-uniform
        #pragma unroll
        for (int r = 0; r < 4; ++r) {
            const int orow = quad * 4 + r;
            const float bias = (ob < 32) ? bq[ob + orow]
                             : (ob < 64) ? bk[ob - 32 + orow]
                                         : bv[ob - 64 + orow];
            if (ob < 64) {                        // q or k -> bf16
                unsigned short* dst = (ob < 32) ? q : k;
                int orel = (ob < 32) ? ob : ob - 32;
                size_t rowbase = ((size_t)b * CR + orel + orow) * HW;
                #pragma unroll
                for (int n = 0; n < 4; ++n)
                    dst[rowbase + hw0 + n * 16 + m16] = f2bf(acc[i][n][r] + bias);
            } else {                              // v, bf16
                size_t rowbase = ((size_t)b * CC + (ob - 64) + orow) * HW;
                #pragma unroll
                for (int n = 0; n < 4; ++n)
                    vv[rowbase + hw0 + n * 16 + m16] = f2bf(acc[i][n][r] + bias);
            }
        }
    }
}

// ---------------------------------------------------------------------------
// K2: MERGED energies + softmax + apply + residual (R11 body, byte-identical
// arithmetic).  CHANGED vs R11 (same single variable): h = hswz(blockIdx.x).
// ---------------------------------------------------------------------------
__global__ __launch_bounds__(512) void attn_apply(
    const unsigned short* __restrict__ q_, const unsigned short* __restrict__ k_,
    const unsigned short* __restrict__ vv,
    const float* __restrict__ x, const float* __restrict__ gamma,
    float* __restrict__ out)
{
    struct PA {
        float qs[64][33];     //  8448 B
        float ks[3][64][33];  // 25344 B
        float es[64][9];      //  2304 B
    };
    struct PV {
        float vs[3][64][73];  // 56064 B  [row][ch][4 zero | 64 px | 4 zero | 1]
    };
    __shared__ union USM { PA a; PV v; } sm;    // 56064 B
    __shared__ float aws[64][13];               //  3328 B (persistent)

    const int h = hswz(blockIdx.x), b = blockIdx.y, t = threadIdx.x;

    // ---- stage q + 3 k-rows (bf16 source) ----
    {
        const int cr = t >> 4, p4 = (t & 15) * 4;   // 512 threads = 32cr x 16px4
        ushort4 uq = *(const ushort4*)&q_[((size_t)b * CR + cr) * HW + h * WIMG + p4];
        sm.a.qs[p4 + 0][cr] = bf2f(uq.x); sm.a.qs[p4 + 1][cr] = bf2f(uq.y);
        sm.a.qs[p4 + 2][cr] = bf2f(uq.z); sm.a.qs[p4 + 3][cr] = bf2f(uq.w);
        #pragma unroll
        for (int r = 0; r < 3; ++r) {
            int hh = h + r - 1;
            ushort4 uk = make_ushort4(0, 0, 0, 0);
            if (hh >= 0 && hh < HIMG)
                uk = *(const ushort4*)&k_[((size_t)b * CR + cr) * HW + hh * WIMG + p4];
            sm.a.ks[r][p4 + 0][cr] = bf2f(uk.x); sm.a.ks[r][p4 + 1][cr] = bf2f(uk.y);
            sm.a.ks[r][p4 + 2][cr] = bf2f(uk.z); sm.a.ks[r][p4 + 3][cr] = bf2f(uk.w);
        }
    }
    __syncthreads();

    // ---- energies ----
    for (int id = t; id < 576; id += 512) {
        int px = id / 9, kk = id - px * 9;
        int di = kk / 3, dj = kk - di * 3;
        int hh = h + di - 1, ww = px + dj - 1;
        float e = 0.f;
        if (hh >= 0 && hh < HIMG && ww >= 0 && ww < WIMG) {
            float s = 0.f;
            #pragma unroll
            for (int c = 0; c < CR; ++c)
                s = fmaf(sm.a.qs[px][c], sm.a.ks[di][ww][c], s);
            e = s;
        }
        sm.a.es[px][kk] = e;
    }
    __syncthreads();

    // ---- softmax -> aws (LDS only) ----
    if (t < 64) {
        float m = sm.a.es[t][0];
        #pragma unroll
        for (int kk = 1; kk < 9; ++kk) m = fmaxf(m, sm.a.es[t][kk]);
        float ex[9]; float ssum = 0.f;
        #pragma unroll
        for (int kk = 0; kk < 9; ++kk) { ex[kk] = __expf(sm.a.es[t][kk] - m); ssum += ex[kk]; }
        float inv = 1.f / ssum;
        #pragma unroll
        for (int kk = 0; kk < 9; ++kk) aws[t][kk] = ex[kk] * inv;
    }
    __syncthreads();   // es reads done -> vs (overlapping a.*) may be written

    // ---- zero vs pads once ----
    if (t < 192) {
        int r = t / 64, c = t - r * 64;
        float* row = &sm.v.vs[r][c][0];
        row[0] = 0.f; row[1] = 0.f; row[2] = 0.f; row[3] = 0.f;
        row[68] = 0.f; row[69] = 0.f; row[70] = 0.f; row[71] = 0.f;
    }

    const int px0 = (t & 15) * 4;
    const int cl  = t >> 4;                 // 0..31
    const float g = gamma[0];
    float w[4][9];
    #pragma unroll
    for (int i = 0; i < 4; ++i)
        #pragma unroll
        for (int kk = 0; kk < 9; ++kk) w[i][kk] = aws[px0 + i][kk];

    // ---- 4 chunks of 64 channels ----
    for (int cb = 0; cb < 4; ++cb) {
        // residual-x prefetch: issue FIRST, consume last (hides HBM latency)
        size_t base0 = ((size_t)b * CC + cb * 64 + cl) * HW + h * WIMG + px0;
        size_t base1 = base0 + (size_t)32 * HW;
        float4 xa0 = *(const float4*)&x[base0];
        float4 xa1 = *(const float4*)&x[base1];

        if (cb) __syncthreads();            // protect vs reuse
        #pragma unroll
        for (int i = 0; i < 6; ++i) {
            int idx = t + 512 * i;          // 0..3071
            int p4 = (idx & 15) * 4, c = (idx >> 4) & 63, r = idx >> 10;
            int hh = h + r - 1;
            float4 val = make_float4(0.f, 0.f, 0.f, 0.f);
            if (hh >= 0 && hh < HIMG) {
                ushort4 u = *(const ushort4*)&vv[((size_t)b * CC + cb * 64 + c) * HW
                                                 + hh * WIMG + p4];
                val = make_float4(bf2f(u.x), bf2f(u.y), bf2f(u.z), bf2f(u.w));
            }
            float* dstp = &sm.v.vs[r][c][4 + p4];
            dstp[0] = val.x; dstp[1] = val.y; dstp[2] = val.z; dstp[3] = val.w;
        }
        __syncthreads();

        #pragma unroll
        for (int ci = 0; ci < 2; ++ci) {
            int c = cl + 32 * ci;
            float a0 = 0.f, a1 = 0.f, a2 = 0.f, a3 = 0.f;
            #pragma unroll
            for (int r = 0; r < 3; ++r) {
                const float* row = &sm.v.vs[r][c][0];
                float lft = row[3 + px0];
                float c0  = row[4 + px0];
                float c1  = row[5 + px0];
                float c2  = row[6 + px0];
                float c3  = row[7 + px0];
                float rgt = row[8 + px0];
                int r3 = r * 3;
                a0 = fmaf(w[0][r3], lft, fmaf(w[0][r3+1], c0, fmaf(w[0][r3+2], c1, a0)));
                a1 = fmaf(w[1][r3], c0,  fmaf(w[1][r3+1], c1, fmaf(w[1][r3+2], c2, a1)));
                a2 = fmaf(w[2][r3], c1,  fmaf(w[2][r3+1], c2, fmaf(w[2][r3+2], c3, a2)));
                a3 = fmaf(w[3][r3], c2,  fmaf(w[3][r3+1], c3, fmaf(w[3][r3+2], rgt, a3)));
            }
            float4 xa = ci ? xa1 : xa0;
            size_t base = ci ? base1 : base0;
            float4 o;
            o.x = fmaf(g, a0, xa.x); o.y = fmaf(g, a1, xa.y);
            o.z = fmaf(g, a2, xa.z); o.w = fmaf(g, a3, xa.w);
            *(float4*)&out[base] = o;
        }
    }
}

extern "C" void kernel_launch(void* const* d_in, const int* in_sizes, int n_in,
                              void* d_out, int out_size, void* d_ws, size_t ws_size,
                              hipStream_t stream)
{
    const float* x     = (const float*)d_in[0];
    const float* Wq    = (const float*)d_in[1];
    const float* bq    = (const float*)d_in[2];
    const float* Wk    = (const float*)d_in[3];
    const float* bk    = (const float*)d_in[4];
    const float* Wv    = (const float*)d_in[5];
    const float* bv    = (const float*)d_in[6];
    const float* gamma = (const float*)d_in[7];
    float* out = (float*)d_out;

    unsigned short* q  = (unsigned short*)d_ws;                //  2.10 MB
    unsigned short* k  = q + (size_t)B_ * CR * HW;             //  2.10 MB
    unsigned short* vv = k + (size_t)B_ * CR * HW;             // 16.78 MB

    proj_gemm<<<dim3(HW / 64, B_), 256, 0, stream>>>(
        Wq, bq, Wk, bk, Wv, bv, x, q, k, vv);
    attn_apply<<<dim3(HIMG, B_), 512, 0, stream>>>(q, k, vv, x, gamma, out);
}

// Round 13
// 124.729 us; speedup vs baseline: 1.0148x; 1.0148x over previous
//
#include <hip/hip_runtime.h>

#define HW   4096
#define HIMG 64
#define WIMG 64
#define CC   256
#define CR   32
#define B_   8

typedef __attribute__((ext_vector_type(8))) short bf16x8;
typedef __attribute__((ext_vector_type(4))) float f32x4;

__device__ inline unsigned short f2bf(float f) {
    union { float f; unsigned u; } v; v.f = f;
    return (unsigned short)((v.u + 0x8000u) >> 16);
}
__device__ inline float bf2f(unsigned short h) {
    union { unsigned u; float f; } v; v.u = ((unsigned)h) << 16; return v.f;
}
__device__ inline unsigned pack2(float a, float b) {
    return (unsigned)f2bf(a) | ((unsigned)f2bf(b) << 16);
}

// ---------------------------------------------------------------------------
// K1: fused transpose+convert+GEMM (R11 verbatim — session best, 125.6 µs).
// R12's h-swizzle was null-to-negative (L3 already absorbs halo reuse);
// reverted per pre-commit.
// ---------------------------------------------------------------------------
__global__ __launch_bounds__(256) void proj_gemm(
    const float* __restrict__ Wq, const float* __restrict__ bq,
    const float* __restrict__ Wk, const float* __restrict__ bk,
    const float* __restrict__ Wv, const float* __restrict__ bv,
    const float* __restrict__ x,
    unsigned short* __restrict__ q, unsigned short* __restrict__ k,
    unsigned short* __restrict__ vv)
{
    __shared__ unsigned short As[320 * 72];
    __shared__ float          xt32[64 * 65];
    __shared__ unsigned short Bs[64 * 64];

    const int b   = blockIdx.y;
    const int hw0 = blockIdx.x * 64;
    const int t    = threadIdx.x;
    const int lane = t & 63, wv = t >> 6;
    const int m16  = lane & 15, quad = lane >> 4;

    f32x4 acc[5][4];
    #pragma unroll
    for (int i = 0; i < 5; ++i)
        #pragma unroll
        for (int n = 0; n < 4; ++n)
            acc[i][n] = (f32x4){0.f, 0.f, 0.f, 0.f};

    for (int kc = 0; kc < 4; ++kc) {
        const int k0 = kc * 64;
        if (kc) __syncthreads();            // protect As/xt32/Bs reuse

        // stage A: 320 rows x 64 ch, fp32 source -> bf16 inline (same f2bf)
        #pragma unroll
        for (int i = 0; i < 10; ++i) {
            int idx = t + 256 * i;          // 0..2559
            int row = idx >> 3, s8 = idx & 7;
            const float* wsrc = (row < 32) ? &Wq[row * CC]
                              : (row < 64) ? &Wk[(row - 32) * CC]
                                           : &Wv[(row - 64) * CC];
            float4 a0 = *(const float4*)&wsrc[k0 + s8 * 8];
            float4 a1 = *(const float4*)&wsrc[k0 + s8 * 8 + 4];
            uint4 u;
            u.x = pack2(a0.x, a0.y); u.y = pack2(a0.z, a0.w);
            u.z = pack2(a1.x, a1.y); u.w = pack2(a1.z, a1.w);
            *(uint4*)&As[row * 72 + s8 * 8] = u;
        }
        // stage x chunk fp32: 64 c x 64 px, coalesced along px
        #pragma unroll
        for (int i = 0; i < 4; ++i) {
            int idx = t + 256 * i;          // 0..1023
            int c = idx >> 4, p4 = (idx & 15) * 4;
            float4 vx = *(const float4*)&x[((size_t)b * CC + k0 + c) * HW + hw0 + p4];
            *(float4*)&xt32[c * 65 + p4] = vx;
        }
        __syncthreads();

        // transpose+convert into Bs: thread -> px = lane, 16 channels
        {
            const int px = lane;
            const int c0 = wv * 16;
            float f[16];
            #pragma unroll
            for (int j = 0; j < 16; ++j)
                f[j] = xt32[(c0 + j) * 65 + px];   // bank (c0+j+px)%32: 2-way
            uint4 w0, w1;
            w0.x = pack2(f[0],  f[1]);  w0.y = pack2(f[2],  f[3]);
            w0.z = pack2(f[4],  f[5]);  w0.w = pack2(f[6],  f[7]);
            w1.x = pack2(f[8],  f[9]);  w1.y = pack2(f[10], f[11]);
            w1.z = pack2(f[12], f[13]); w1.w = pack2(f[14], f[15]);
            const int lg0 = c0 >> 3, sw = px & 7;
            *(uint4*)&Bs[px * 64 + ((lg0     ^ sw) * 8)] = w0;
            *(uint4*)&Bs[px * 64 + (((lg0+1) ^ sw) * 8)] = w1;
        }
        __syncthreads();

        #pragma unroll
        for (int ks = 0; ks < 2; ++ks) {
            bf16x8 af[5], bf[4];
            #pragma unroll
            for (int i = 0; i < 5; ++i)
                af[i] = *(const bf16x8*)&As[((wv * 5 + i) * 16 + m16) * 72
                                            + ks * 32 + quad * 8];
            #pragma unroll
            for (int n = 0; n < 4; ++n) {
                int px = n * 16 + m16;
                int lg = ks * 4 + quad;
                bf[n] = *(const bf16x8*)&Bs[px * 64 + ((lg ^ (px & 7)) * 8)];
            }
            #pragma unroll
            for (int i = 0; i < 5; ++i)
                #pragma unroll
                for (int n = 0; n < 4; ++n)
                    acc[i][n] = __builtin_amdgcn_mfma_f32_16x16x32_bf16(
                        af[i], bf[n], acc[i][n], 0, 0, 0);
        }
    }

    // epilogue: D row = quad*4+reg, col = lane&15; biases direct from inputs
    #pragma unroll
    for (int i = 0; i < 5; ++i) {
        const int ob = (wv * 5 + i) * 16;        // 0..304, wave-uniform
        #pragma unroll
        for (int r = 0; r < 4; ++r) {
            const int orow = quad * 4 + r;
            const float bias = (ob < 32) ? bq[ob + orow]
                             : (ob < 64) ? bk[ob - 32 + orow]
                                         : bv[ob - 64 + orow];
            if (ob < 64) {                        // q or k -> bf16
                unsigned short* dst = (ob < 32) ? q : k;
                int orel = (ob < 32) ? ob : ob - 32;
                size_t rowbase = ((size_t)b * CR + orel + orow) * HW;
                #pragma unroll
                for (int n = 0; n < 4; ++n)
                    dst[rowbase + hw0 + n * 16 + m16] = f2bf(acc[i][n][r] + bias);
            } else {                              // v, bf16
                size_t rowbase = ((size_t)b * CC + (ob - 64) + orow) * HW;
                #pragma unroll
                for (int n = 0; n < 4; ++n)
                    vv[rowbase + hw0 + n * 16 + m16] = f2bf(acc[i][n][r] + bias);
            }
        }
    }
}

// ---------------------------------------------------------------------------
// K2: MERGED energies + softmax + apply + residual (R11 verbatim).
// ---------------------------------------------------------------------------
__global__ __launch_bounds__(512) void attn_apply(
    const unsigned short* __restrict__ q_, const unsigned short* __restrict__ k_,
    const unsigned short* __restrict__ vv,
    const float* __restrict__ x, const float* __restrict__ gamma,
    float* __restrict__ out)
{
    struct PA {
        float qs[64][33];     //  8448 B
        float ks[3][64][33];  // 25344 B
        float es[64][9];      //  2304 B
    };
    struct PV {
        float vs[3][64][73];  // 56064 B  [row][ch][4 zero | 64 px | 4 zero | 1]
    };
    __shared__ union USM { PA a; PV v; } sm;    // 56064 B
    __shared__ float aws[64][13];               //  3328 B (persistent)

    const int h = blockIdx.x, b = blockIdx.y, t = threadIdx.x;

    // ---- stage q + 3 k-rows (bf16 source) ----
    {
        const int cr = t >> 4, p4 = (t & 15) * 4;   // 512 threads = 32cr x 16px4
        ushort4 uq = *(const ushort4*)&q_[((size_t)b * CR + cr) * HW + h * WIMG + p4];
        sm.a.qs[p4 + 0][cr] = bf2f(uq.x); sm.a.qs[p4 + 1][cr] = bf2f(uq.y);
        sm.a.qs[p4 + 2][cr] = bf2f(uq.z); sm.a.qs[p4 + 3][cr] = bf2f(uq.w);
        #pragma unroll
        for (int r = 0; r < 3; ++r) {
            int hh = h + r - 1;
            ushort4 uk = make_ushort4(0, 0, 0, 0);
            if (hh >= 0 && hh < HIMG)
                uk = *(const ushort4*)&k_[((size_t)b * CR + cr) * HW + hh * WIMG + p4];
            sm.a.ks[r][p4 + 0][cr] = bf2f(uk.x); sm.a.ks[r][p4 + 1][cr] = bf2f(uk.y);
            sm.a.ks[r][p4 + 2][cr] = bf2f(uk.z); sm.a.ks[r][p4 + 3][cr] = bf2f(uk.w);
        }
    }
    __syncthreads();

    // ---- energies ----
    for (int id = t; id < 576; id += 512) {
        int px = id / 9, kk = id - px * 9;
        int di = kk / 3, dj = kk - di * 3;
        int hh = h + di - 1, ww = px + dj - 1;
        float e = 0.f;
        if (hh >= 0 && hh < HIMG && ww >= 0 && ww < WIMG) {
            float s = 0.f;
            #pragma unroll
            for (int c = 0; c < CR; ++c)
                s = fmaf(sm.a.qs[px][c], sm.a.ks[di][ww][c], s);
            e = s;
        }
        sm.a.es[px][kk] = e;
    }
    __syncthreads();

    // ---- softmax -> aws (LDS only) ----
    if (t < 64) {
        float m = sm.a.es[t][0];
        #pragma unroll
        for (int kk = 1; kk < 9; ++kk) m = fmaxf(m, sm.a.es[t][kk]);
        float ex[9]; float ssum = 0.f;
        #pragma unroll
        for (int kk = 0; kk < 9; ++kk) { ex[kk] = __expf(sm.a.es[t][kk] - m); ssum += ex[kk]; }
        float inv = 1.f / ssum;
        #pragma unroll
        for (int kk = 0; kk < 9; ++kk) aws[t][kk] = ex[kk] * inv;
    }
    __syncthreads();   // es reads done -> vs (overlapping a.*) may be written

    // ---- zero vs pads once ----
    if (t < 192) {
        int r = t / 64, c = t - r * 64;
        float* row = &sm.v.vs[r][c][0];
        row[0] = 0.f; row[1] = 0.f; row[2] = 0.f; row[3] = 0.f;
        row[68] = 0.f; row[69] = 0.f; row[70] = 0.f; row[71] = 0.f;
    }

    const int px0 = (t & 15) * 4;
    const int cl  = t >> 4;                 // 0..31
    const float g = gamma[0];
    float w[4][9];
    #pragma unroll
    for (int i = 0; i < 4; ++i)
        #pragma unroll
        for (int kk = 0; kk < 9; ++kk) w[i][kk] = aws[px0 + i][kk];

    // ---- 4 chunks of 64 channels ----
    for (int cb = 0; cb < 4; ++cb) {
        // residual-x prefetch: issue FIRST, consume last (hides HBM latency)
        size_t base0 = ((size_t)b * CC + cb * 64 + cl) * HW + h * WIMG + px0;
        size_t base1 = base0 + (size_t)32 * HW;
        float4 xa0 = *(const float4*)&x[base0];
        float4 xa1 = *(const float4*)&x[base1];

        if (cb) __syncthreads();            // protect vs reuse
        #pragma unroll
        for (int i = 0; i < 6; ++i) {
            int idx = t + 512 * i;          // 0..3071
            int p4 = (idx & 15) * 4, c = (idx >> 4) & 63, r = idx >> 10;
            int hh = h + r - 1;
            float4 val = make_float4(0.f, 0.f, 0.f, 0.f);
            if (hh >= 0 && hh < HIMG) {
                ushort4 u = *(const ushort4*)&vv[((size_t)b * CC + cb * 64 + c) * HW
                                                 + hh * WIMG + p4];
                val = make_float4(bf2f(u.x), bf2f(u.y), bf2f(u.z), bf2f(u.w));
            }
            float* dstp = &sm.v.vs[r][c][4 + p4];
            dstp[0] = val.x; dstp[1] = val.y; dstp[2] = val.z; dstp[3] = val.w;
        }
        __syncthreads();

        #pragma unroll
        for (int ci = 0; ci < 2; ++ci) {
            int c = cl + 32 * ci;
            float a0 = 0.f, a1 = 0.f, a2 = 0.f, a3 = 0.f;
            #pragma unroll
            for (int r = 0; r < 3; ++r) {
                const float* row = &sm.v.vs[r][c][0];
                float lft = row[3 + px0];
                float c0  = row[4 + px0];
                float c1  = row[5 + px0];
                float c2  = row[6 + px0];
                float c3  = row[7 + px0];
                float rgt = row[8 + px0];
                int r3 = r * 3;
                a0 = fmaf(w[0][r3], lft, fmaf(w[0][r3+1], c0, fmaf(w[0][r3+2], c1, a0)));
                a1 = fmaf(w[1][r3], c0,  fmaf(w[1][r3+1], c1, fmaf(w[1][r3+2], c2, a1)));
                a2 = fmaf(w[2][r3], c1,  fmaf(w[2][r3+1], c2, fmaf(w[2][r3+2], c3, a2)));
                a3 = fmaf(w[3][r3], c2,  fmaf(w[3][r3+1], c3, fmaf(w[3][r3+2], rgt, a3)));
            }
            float4 xa = ci ? xa1 : xa0;
            size_t base = ci ? base1 : base0;
            float4 o;
            o.x = fmaf(g, a0, xa.x); o.y = fmaf(g, a1, xa.y);
            o.z = fmaf(g, a2, xa.z); o.w = fmaf(g, a3, xa.w);
            *(float4*)&out[base] = o;
        }
    }
}

extern "C" void kernel_launch(void* const* d_in, const int* in_sizes, int n_in,
                              void* d_out, int out_size, void* d_ws, size_t ws_size,
                              hipStream_t stream)
{
    const float* x     = (const float*)d_in[0];
    const float* Wq    = (const float*)d_in[1];
    const float* bq    = (const float*)d_in[2];
    const float* Wk    = (const float*)d_in[3];
    const float* bk    = (const float*)d_in[4];
    const float* Wv    = (const float*)d_in[5];
    const float* bv    = (const float*)d_in[6];
    const float* gamma = (const float*)d_in[7];
    float* out = (float*)d_out;

    unsigned short* q  = (unsigned short*)d_ws;                //  2.10 MB
    unsigned short* k  = q + (size_t)B_ * CR * HW;             //  2.10 MB
    unsigned short* vv = k + (size_t)B_ * CR * HW;             // 16.78 MB

    proj_gemm<<<dim3(HW / 64, B_), 256, 0, stream>>>(
        Wq, bq, Wk, bk, Wv, bv, x, q, k, vv);
    attn_apply<<<dim3(HIMG, B_), 512, 0, stream>>>(q, k, vv, x, gamma, out);
}